// Round 18
// baseline (410.352 us; speedup 1.0000x reference)
//
#include <hip/hip_runtime.h>
#include <hip/hip_bf16.h>
#include <math.h>

#define EPS 1e-5f
#define SLOPE 0.2f

// ---------------------------------------------------------------------------
//  L1: [512,  1,48,80] -> [512, 64,24,40]
//  L2: [512, 64,24,40] -> [512,128,12,20]
//  L3: [512,128,12,20] -> [512,256, 6,10]
//  L4: [512,256, 6,10] -> [512,512, 3, 5]
// bf16 NHWC. Conv2-4 = MFMA implicit GEMM, BM=128 BN=64, BK templated
// (L2=64 CIN-bound; L3/L4=128, SWM=CPR-1 swizzle — round-17 fixed the
// 16-chunk mask, conflicts 5.9e6 -> 0). global_load_lds w=16 staging
// (linear dest + pre-swizzled source + XOR read). Per-pixel validity
// bitmask + wave-uniform k-offset. Round-18: BN stage-1 fused into conv1
// (shuffle-butterfly epilogue; reduceB launch + 63MB re-read eliminated)
// and weight-prep merged into the conv1 launch. KS=1, XCD swizzle.
// ---------------------------------------------------------------------------

typedef short bf16x8 __attribute__((ext_vector_type(8)));
typedef short short4v __attribute__((ext_vector_type(4)));
typedef float f32x4 __attribute__((ext_vector_type(4)));

__device__ __forceinline__ float bf2f(short s) {
    unsigned int u = ((unsigned int)(unsigned short)s) << 16;
    float f;
    __builtin_memcpy(&f, &u, 4);
    return f;
}
__device__ __forceinline__ short f2bf(float f) {
    unsigned int u;
    __builtin_memcpy(&u, &f, 4);
    u = (u + 0x7FFFu + ((u >> 16) & 1u)) >> 16;   // RNE
    return (short)(unsigned short)u;
}

// 16B async global->LDS. lds ptr must be wave-uniform; HW adds lane*16.
__device__ __forceinline__ void gload16_lds(const short* g, short* l) {
    __builtin_amdgcn_global_load_lds(
        (__attribute__((address_space(1))) void*)(short*)g,
        (__attribute__((address_space(3))) void*)l, 16, 0, 0);
}

// ---- weight cast+reorder helper: OIHW fp32 -> bf16 [co][kp*I + ci] ----
template<int I>
__device__ __forceinline__ void twk_one(const float* __restrict__ W,
                                        short* __restrict__ wB, int idx) {
    constexpr int K = I * 16;
    int co = idx / K;
    int rem = idx % K;
    int kp = rem / I;
    int ci = rem % I;
    wB[idx] = f2bf(W[((size_t)co * I + ci) * 16 + kp]);
}

// ---- conv1 (blocks < 1920) + weight prep (blocks >= 1920), one launch ----
// conv1: pixel-per-lane, 64 cout/thread, W1 in LDS; BN stage-1 fused via
// 64-lane shuffle butterfly (deterministic) -> part[bid*128 + {s[64],q[64]}].
__global__ __launch_bounds__(256) void conv1F_k(const float* __restrict__ x,
                                                const float* __restrict__ W1,
                                                short* __restrict__ out,
                                                float* __restrict__ part,
                                                const float* __restrict__ W2,
                                                const float* __restrict__ W3,
                                                const float* __restrict__ W4,
                                                short* __restrict__ wB2,
                                                short* __restrict__ wB3,
                                                short* __restrict__ wB4) {
    const int blk = (int)blockIdx.x;
    const int t = threadIdx.x;
    if (blk >= 1920) {                    // weight-prep blocks
        int idx = (blk - 1920) * 256 + t; // 10752*256 = 2752512 ids
        if (idx < 131072) {
            twk_one<64>(W2, wB2, idx);
        } else if (idx < 655360) {
            twk_one<128>(W3, wB3, idx - 131072);
        } else {
            twk_one<256>(W4, wB4, idx - 655360);
        }
        return;
    }

    __shared__ float wlds[1024];          // W1 [64 co][16 k] fp32
    __shared__ float red[4][128];         // per-wave {s[64], q[64]}
    ((float4*)wlds)[t] = ((const float4*)W1)[t];
    __syncthreads();

    int pixel = blk * 256 + t;            // 512*24*40 = 491520 pixels
    int n  = pixel / 960;
    int p  = pixel % 960;
    int oh = p / 40, ow = p % 40;
    int ih0 = oh * 2 - 1, iw0 = ow * 2 - 1;
    const int w = t >> 6, l = t & 63;

    float patch[16];
#pragma unroll
    for (int kh = 0; kh < 4; ++kh) {
        int ih = ih0 + kh;
#pragma unroll
        for (int kw = 0; kw < 4; ++kw) {
            int iw = iw0 + kw;
            bool ok = ((unsigned)ih < 48u) && ((unsigned)iw < 80u);
            patch[kh * 4 + kw] = ok ? x[((size_t)n * 48 + ih) * 80 + iw] : 0.f;
        }
    }
#pragma unroll
    for (int cog = 0; cog < 8; ++cog) {
        bf16x8 v;
        float s8[8], q8[8];
#pragma unroll
        for (int j = 0; j < 8; ++j) {
            const float4* wv = (const float4*)(wlds + (cog * 8 + j) * 16);
            float4 w0 = wv[0], w1 = wv[1], w2 = wv[2], w3 = wv[3];
            float a = 0.f;
            a = fmaf(patch[0],  w0.x, a); a = fmaf(patch[1],  w0.y, a);
            a = fmaf(patch[2],  w0.z, a); a = fmaf(patch[3],  w0.w, a);
            a = fmaf(patch[4],  w1.x, a); a = fmaf(patch[5],  w1.y, a);
            a = fmaf(patch[6],  w1.z, a); a = fmaf(patch[7],  w1.w, a);
            a = fmaf(patch[8],  w2.x, a); a = fmaf(patch[9],  w2.y, a);
            a = fmaf(patch[10], w2.z, a); a = fmaf(patch[11], w2.w, a);
            a = fmaf(patch[12], w3.x, a); a = fmaf(patch[13], w3.y, a);
            a = fmaf(patch[14], w3.z, a); a = fmaf(patch[15], w3.w, a);
            v[j] = f2bf(a);
            float fj = bf2f(v[j]);        // bf16-rounded (parity w/ old reduceB)
            s8[j] = fj; q8[j] = fj * fj;
        }
        *(bf16x8*)(out + (size_t)pixel * 64 + cog * 8) = v;
        // deterministic 64-lane butterfly per channel
#pragma unroll
        for (int d = 1; d < 64; d <<= 1) {
#pragma unroll
            for (int j = 0; j < 8; ++j) {
                s8[j] += __shfl_xor(s8[j], d, 64);
                q8[j] += __shfl_xor(q8[j], d, 64);
            }
        }
        if (l == 0) {
#pragma unroll
            for (int j = 0; j < 8; ++j) {
                red[w][cog * 8 + j]      = s8[j];
                red[w][64 + cog * 8 + j] = q8[j];
            }
        }
    }
    __syncthreads();
    if (t < 128) {
        float r = red[0][t] + red[1][t] + red[2][t] + red[3][t];
        part[(size_t)blk * 128 + t] = r;
    }
}

// ---- conv2-4: MFMA implicit GEMM, BK templated, DMA staging, XCD swizzle ----
template<int BKT, int CIN, int COUT, int IH, int IW, int OH, int OW>
__global__ __launch_bounds__(256, 4) void convM_k(const short* __restrict__ in,
                                                  const short* __restrict__ wB,
                                                  short* __restrict__ out,
                                                  float* __restrict__ part,
                                                  const short* __restrict__ zbuf) {
    constexpr int K  = CIN * 16;
    constexpr int NT = K / BKT;
    constexpr int BM = 128, BN = 64;
    constexpr int CPR = BKT / 8;          // chunks per row (8 or 16)
    constexpr int SWM = CPR - 1;          // swizzle mask (7 or 15)
    constexpr int RPS = 256 / CPR;        // rows per staging set
    constexpr int RPW = 64 / CPR;         // rows per wave per set
    constexpr int ASETS = BM / RPS;
    constexpr int BSETS = BN / RPS;
    constexpr int nTN = COUT / BN;
    constexpr int M = 512 * OH * OW;
    constexpr int NWG = (M / BM) * nTN;   // divisible by 8 for all layers
    __shared__ short As[BM * BKT];
    __shared__ short Bs[BN * BKT];

    const int t = threadIdx.x;
    const int b = (int)blockIdx.x;
    const int lid = (b & 7) * (NWG >> 3) + (b >> 3);
    const int bn = lid % nTN;
    const int bm = lid / nTN;
    const int m0 = bm * BM, n0 = bn * BN;

    const int w = t >> 6, l = t & 63;
    const int c   = t % CPR;
    const int rs  = t / CPR;
    const int rowlane = w * RPW + (l / CPR);
    const int ccs = c ^ (rowlane & SWM);  // pre-swizzled source chunk
    long aoff[ASETS];
    unsigned amask[ASETS];
#pragma unroll
    for (int i = 0; i < ASETS; ++i) {
        int row = i * RPS + rs;
        int gr = m0 + row;
        int n = gr / (OH * OW), p = gr % (OH * OW);
        int ph = (p / OW) * 2 - 1, pw = (p % OW) * 2 - 1;
        aoff[i] = ((long)n * IH * IW + (long)ph * IW + pw) * CIN + ccs * 8;
        unsigned m = 0;
#pragma unroll
        for (int kp = 0; kp < 16; ++kp) {
            int ih = ph + (kp >> 2), iw = pw + (kp & 3);
            if ((unsigned)ih < (unsigned)IH && (unsigned)iw < (unsigned)IW)
                m |= 1u << kp;
        }
        amask[i] = m;
    }
    long boff[BSETS];
#pragma unroll
    for (int i = 0; i < BSETS; ++i)
        boff[i] = (long)(n0 + i * RPS + rs) * K + ccs * 8;

    const int wr = (w >> 1) * 64, wc = (w & 1) * 32;
    const int fr = l & 15, kq = l >> 4;

    f32x4 acc[4][2];
#pragma unroll
    for (int mi = 0; mi < 4; ++mi)
#pragma unroll
        for (int ni = 0; ni < 2; ++ni) acc[mi][ni] = 0;

    for (int kt = 0; kt < NT; ++kt) {
        const int kk0 = kt * BKT;
        const int kp = kk0 / CIN, ci0 = kk0 % CIN;
        const long koff = ((long)(kp >> 2) * IW + (kp & 3)) * CIN + ci0;  // uniform
        __syncthreads();                  // all waves done reading LDS (prev kt)
#pragma unroll
        for (int i = 0; i < ASETS; ++i) {
            const short* src = ((amask[i] >> kp) & 1u)
                ? in + aoff[i] + koff : zbuf;
            gload16_lds(src, As + (i * RPS + w * RPW) * BKT);
        }
#pragma unroll
        for (int i = 0; i < BSETS; ++i)
            gload16_lds(wB + boff[i] + kk0, Bs + (i * RPS + w * RPW) * BKT);
        __syncthreads();                  // compiler drains vmcnt(0) pre-barrier
#pragma unroll
        for (int kk = 0; kk < BKT / 32; ++kk) {
            const int kidx = kk * 4 + kq;
            bf16x8 af[4], bfr[2];
#pragma unroll
            for (int mi = 0; mi < 4; ++mi) {
                int row = wr + mi * 16 + fr;
                af[mi] = *(const bf16x8*)(As + row * BKT + ((kidx ^ (row & SWM)) * 8));
            }
#pragma unroll
            for (int ni = 0; ni < 2; ++ni) {
                int row = wc + ni * 16 + fr;
                bfr[ni] = *(const bf16x8*)(Bs + row * BKT + ((kidx ^ (row & SWM)) * 8));
            }
#pragma unroll
            for (int mi = 0; mi < 4; ++mi)
#pragma unroll
                for (int ni = 0; ni < 2; ++ni)
                    acc[mi][ni] = __builtin_amdgcn_mfma_f32_16x16x32_bf16(
                        af[mi], bfr[ni], acc[mi][ni], 0, 0, 0);
        }
    }

    // bf16 output (D: row = kq*4+r, col = fr) + fused BN stage-1
#pragma unroll
    for (int mi = 0; mi < 4; ++mi)
#pragma unroll
        for (int ni = 0; ni < 2; ++ni)
#pragma unroll
            for (int r = 0; r < 4; ++r) {
                int row = m0 + wr + mi * 16 + kq * 4 + r;
                int col = n0 + wc + ni * 16 + fr;
                out[(size_t)row * COUT + col] = f2bf(acc[mi][ni][r]);
            }
    __syncthreads();                      // done reading As before aliasing
    float* red = (float*)As;              // 8 slots * 64 ch * 2 = 4 KB
#pragma unroll
    for (int ni = 0; ni < 2; ++ni) {
        float s = 0.f, q = 0.f;
#pragma unroll
        for (int mi = 0; mi < 4; ++mi)
#pragma unroll
            for (int r = 0; r < 4; ++r) {
                float v = acc[mi][ni][r];
                s += v; q = fmaf(v, v, q);
            }
        int slot = (w >> 1) * 4 + kq;
        int ch = wc + ni * 16 + fr;
        red[(slot * 64 + ch) * 2 + 0] = s;
        red[(slot * 64 + ch) * 2 + 1] = q;
    }
    __syncthreads();
    if (t < 64) {
        float s = 0.f, q = 0.f;
#pragma unroll
        for (int slot = 0; slot < 8; ++slot) {
            s += red[(slot * 64 + t) * 2 + 0];
            q += red[(slot * 64 + t) * 2 + 1];
        }
        part[(size_t)lid * 128 + t]      = s;    // logical-id indexed
        part[(size_t)lid * 128 + 64 + t] = q;
    }
}

// ---- parallel stage-2 fold (stride-2C-per-block layout) ----
template<int C, int P>
__global__ __launch_bounds__(1024) void statsP_k(const float* __restrict__ part,
                                                 const float* __restrict__ gamma,
                                                 const float* __restrict__ beta,
                                                 float* __restrict__ st,
                                                 int nblocks, float invR) {
    int t = threadIdx.x;
    int c = t % C, j = t / C;
    float s = 0.f, q = 0.f;
    for (int b = j; b < nblocks; b += P) {
        s += part[(size_t)b * 2 * C + c];
        q += part[(size_t)b * 2 * C + C + c];
    }
    __shared__ float ls[1024], lq[1024];
    ls[t] = s; lq[t] = q; __syncthreads();
    for (int d = C * P / 2; d >= C; d >>= 1) {
        if (t < d) { ls[t] += ls[t + d]; lq[t] += lq[t + d]; }
        __syncthreads();
    }
    if (t < C) {
        float mean = ls[t] * invR;
        float var  = lq[t] * invR - mean * mean;
        float sc = gamma[t] * rsqrtf(var + EPS);
        st[t]     = sc;
        st[C + t] = beta[t] - mean * sc;
    }
}

// ---- parallel stage-2 fold, convM fused-epilogue layout (2*64 per lid) ----
template<int C, int BNp, int P>
__global__ __launch_bounds__(1024) void stats2P_k(const float* __restrict__ part,
                                                  const float* __restrict__ gamma,
                                                  const float* __restrict__ beta,
                                                  float* __restrict__ st,
                                                  int nTM, float invR) {
    constexpr int NTN = C / BNp;
    int t = threadIdx.x;
    int c = t % C, j = t / C;
    int bn = c / BNp, cc = c % BNp;
    float s = 0.f, q = 0.f;
    for (int bm = j; bm < nTM; bm += P) {
        size_t idx = (size_t)(bm * NTN + bn) * (2 * BNp);
        s += part[idx + cc];
        q += part[idx + BNp + cc];
    }
    __shared__ float ls[1024], lq[1024];
    ls[t] = s; lq[t] = q; __syncthreads();
    for (int d = C * P / 2; d >= C; d >>= 1) {
        if (t < d) { ls[t] += ls[t + d]; lq[t] += lq[t + d]; }
        __syncthreads();
    }
    if (t < C) {
        float mean = ls[t] * invR;
        float var  = lq[t] * invR - mean * mean;
        float sc = gamma[t] * rsqrtf(var + EPS);
        st[t]     = sc;
        st[C + t] = beta[t] - mean * sc;
    }
}

// ---- in-place bf16 normalize + LeakyReLU ----
template<int C>
__global__ __launch_bounds__(256) void scaleB_k(short* __restrict__ h,
                                                const float* __restrict__ st,
                                                size_t n8) {
    __shared__ float sst[1024];
    int t = threadIdx.x;
    for (int j = t; j < 2 * C; j += 256) sst[j] = st[j];
    __syncthreads();
    size_t i = (size_t)blockIdx.x * 256 + t;
    size_t stride = (size_t)gridDim.x * 256;
    bf16x8* h8 = (bf16x8*)h;
    for (; i < n8; i += stride) {
        bf16x8 v = h8[i];
        int c0 = (int)((i * 8) & (size_t)(C - 1));
#pragma unroll
        for (int j = 0; j < 8; ++j) {
            float f = bf2f(v[j]);
            f = fmaf(f, sst[c0 + j], sst[C + c0 + j]);
            f = fmaxf(f, SLOPE * f);
            v[j] = f2bf(f);
        }
        h8[i] = v;
    }
}

// ---- expert head with fused st4 normalize+lrelu ----
__global__ __launch_bounds__(256) void head_k(const short* __restrict__ h4,
                                              const float* __restrict__ W5,
                                              const int* __restrict__ y,
                                              const float* __restrict__ st,
                                              float* __restrict__ out) {
    __shared__ float sst[1024];
    int t = threadIdx.x;
#pragma unroll
    for (int j = 0; j < 4; ++j) sst[t + j * 256] = st[t + j * 256];
    __syncthreads();
    int b = blockIdx.x;
    int e = y[b];
    const float* wp = W5 + (size_t)e * 7680;   // [512][3][5]: c*15 + hw
    const short* hb = h4 + (size_t)b * 7680;   // NHWC: hw*512 + c
    float s = 0.f;
    for (int f = t; f < 7680; f += 256) {
        int c  = f & 511;
        int hw = f >> 9;
        float hv = bf2f(hb[f]);
        hv = fmaf(hv, sst[c], sst[512 + c]);
        hv = fmaxf(hv, SLOPE * hv);
        s = fmaf(hv, wp[c * 15 + hw], s);
    }
    __shared__ float ls[256];
    ls[t] = s; __syncthreads();
    for (int d = 128; d > 0; d >>= 1) {
        if (t < d) ls[t] += ls[t + d];
        __syncthreads();
    }
    if (t == 0) out[b] = ls[0];
}

extern "C" void kernel_launch(void* const* d_in, const int* in_sizes, int n_in,
                              void* d_out, int out_size, void* d_ws, size_t ws_size,
                              hipStream_t stream) {
    const float* x  = (const float*)d_in[0];
    const float* W1 = (const float*)d_in[1];
    const float* g1 = (const float*)d_in[2];
    const float* b1 = (const float*)d_in[3];
    const float* W2 = (const float*)d_in[4];
    const float* g2 = (const float*)d_in[5];
    const float* b2 = (const float*)d_in[6];
    const float* W3 = (const float*)d_in[7];
    const float* g3 = (const float*)d_in[8];
    const float* b3 = (const float*)d_in[9];
    const float* W4 = (const float*)d_in[10];
    const float* g4 = (const float*)d_in[11];
    const float* b4 = (const float*)d_in[12];
    const float* W5 = (const float*)d_in[13];
    const int*   y  = (const int*)d_in[14];
    float* out = (float*)d_out;

    const size_t H1 = (size_t)512 * 24 * 40 * 64;
    const size_t H2 = (size_t)512 * 12 * 20 * 128;
    const size_t H3 = (size_t)512 * 6  * 10 * 256;
    const size_t H4 = (size_t)512 * 3  * 5  * 512;

    float* ws = (float*)d_ws;
    short* h1b = (short*)ws;
    short* h2b = (short*)(ws + H1 / 2);
    short* h3b = (short*)(ws + H1 / 2 + H2 / 2);
    short* h4b = (short*)(ws + H1 / 2 + H2 / 2 + H3 / 2);
    float* fbase = ws + H1 / 2 + H2 / 2 + H3 / 2 + H4 / 2;
    short* wB2 = (short*)fbase;                       // 131072 sh
    short* wB3 = (short*)(fbase + 65536);             // 524288 sh
    short* wB4 = (short*)(fbase + 65536 + 262144);    // 2097152 sh
    float* part = fbase + 65536 + 262144 + 1048576;   // 524288 f
    float* st1 = part + 524288;
    float* st2 = st1 + 128;
    float* st3 = st2 + 256;
    float* st4 = st3 + 512;
    float* zbuf = st4 + 1024;                         // 16 f = 64 B zero page

    // zero page for OOB staging reads (graph-capture-safe memset)
    hipMemsetAsync(zbuf, 0, 64, stream);

    // ---- L1 + weight prep (one launch: 1920 conv blocks + 10752 twk) ----
    conv1F_k<<<1920 + 10752, 256, 0, stream>>>(x, W1, h1b, part,
                                               W2, W3, W4, wB2, wB3, wB4);
    {
        int R = 512 * 24 * 40;
        statsP_k<64, 16><<<1, 1024, 0, stream>>>(part, g1, b1, st1, 1920, 1.f / R);
        scaleB_k<64><<<2048, 256, 0, stream>>>(h1b, st1, H1 / 8);
    }
    // ---- L2 ----  BK=64 (CIN bound): 960 m x 2 n = 1920 blocks
    convM_k<64, 64, 128, 24, 40, 12, 20><<<1920, 256, 0, stream>>>(
        h1b, wB2, h2b, part, (const short*)zbuf);
    {
        float invR = 1.f / (512 * 12 * 20);
        stats2P_k<128, 64, 8><<<1, 1024, 0, stream>>>(part, g2, b2, st2, 960, invR);
        scaleB_k<128><<<2048, 256, 0, stream>>>(h2b, st2, H2 / 8);
    }
    // ---- L3 ----  BK=128: 240 m x 4 n = 960 blocks, NT=16
    convM_k<128, 128, 256, 12, 20, 6, 10><<<960, 256, 0, stream>>>(
        h2b, wB3, h3b, part, (const short*)zbuf);
    {
        float invR = 1.f / (512 * 6 * 10);
        stats2P_k<256, 64, 4><<<1, 1024, 0, stream>>>(part, g3, b3, st3, 240, invR);
        scaleB_k<256><<<2048, 256, 0, stream>>>(h3b, st3, H3 / 8);
    }
    // ---- L4 ----  BK=128: 60 m x 8 n = 480 blocks, NT=32
    convM_k<128, 256, 512, 6, 10, 3, 5><<<480, 256, 0, stream>>>(
        h3b, wB4, h4b, part, (const short*)zbuf);
    {
        float invR = 1.f / (512 * 3 * 5);
        stats2P_k<512, 64, 2><<<1, 1024, 0, stream>>>(part, g4, b4, st4, 60, invR);
    }
    // ---- head (st4 fused) ----
    head_k<<<512, 256, 0, stream>>>(h4b, W5, y, st4, out);
}

// Round 19
// 347.830 us; speedup vs baseline: 1.1797x; 1.1797x over previous
//
#include <hip/hip_runtime.h>
#include <hip/hip_bf16.h>
#include <math.h>

#define EPS 1e-5f
#define SLOPE 0.2f

// ---------------------------------------------------------------------------
//  L1: [512,  1,48,80] -> [512, 64,24,40]
//  L2: [512, 64,24,40] -> [512,128,12,20]
//  L3: [512,128,12,20] -> [512,256, 6,10]
//  L4: [512,256, 6,10] -> [512,512, 3, 5]
// bf16 NHWC. Conv2-4 = MFMA implicit GEMM, BM=128 BN=64, BK templated
// (L2=64 CIN-bound; L3/L4=128, SWM=CPR-1 swizzle, 0 bank conflicts).
// global_load_lds w=16 staging (linear dest + pre-swizzled source + XOR
// read, rule #21). Per-pixel validity bitmask + wave-uniform k-offset.
// OOB -> 64B zero page. KS=1, XCD-chunked swizzle, fused BN stage-1 in
// convM epilogue. ROUND-19: pure revert to round-17 best (349.3us) —
// round-18's conv1 shuffle-butterfly fusion cost 1536 VALU ops/thread +
// scratch spills (112us conv1, +61us total). conv1-stats fusion closed.
// ---------------------------------------------------------------------------

typedef short bf16x8 __attribute__((ext_vector_type(8)));
typedef short short4v __attribute__((ext_vector_type(4)));
typedef float f32x4 __attribute__((ext_vector_type(4)));

__device__ __forceinline__ float bf2f(short s) {
    unsigned int u = ((unsigned int)(unsigned short)s) << 16;
    float f;
    __builtin_memcpy(&f, &u, 4);
    return f;
}
__device__ __forceinline__ short f2bf(float f) {
    unsigned int u;
    __builtin_memcpy(&u, &f, 4);
    u = (u + 0x7FFFu + ((u >> 16) & 1u)) >> 16;   // RNE
    return (short)(unsigned short)u;
}

// 16B async global->LDS. lds ptr must be wave-uniform; HW adds lane*16.
__device__ __forceinline__ void gload16_lds(const short* g, short* l) {
    __builtin_amdgcn_global_load_lds(
        (__attribute__((address_space(1))) void*)(short*)g,
        (__attribute__((address_space(3))) void*)l, 16, 0, 0);
}

// ---- merged weight cast+reorder: OIHW fp32 -> bf16 [co][kp*I + ci] ----
template<int I>
__device__ __forceinline__ void twk_one(const float* __restrict__ W,
                                        short* __restrict__ wB, int idx) {
    constexpr int K = I * 16;
    int co = idx / K;
    int rem = idx % K;
    int kp = rem / I;
    int ci = rem % I;
    wB[idx] = f2bf(W[((size_t)co * I + ci) * 16 + kp]);
}

__global__ __launch_bounds__(256) void twkAll_k(const float* __restrict__ W2,
                                                const float* __restrict__ W3,
                                                const float* __restrict__ W4,
                                                short* __restrict__ wB2,
                                                short* __restrict__ wB3,
                                                short* __restrict__ wB4) {
    int idx = blockIdx.x * 256 + threadIdx.x;
    if (idx < 131072) {
        twk_one<64>(W2, wB2, idx);
    } else if (idx < 131072 + 524288) {
        twk_one<128>(W3, wB3, idx - 131072);
    } else {
        twk_one<256>(W4, wB4, idx - 655360);
    }
}

// ---- conv1: pixel-per-lane, all 64 cout per thread, W1 in LDS ----
__global__ __launch_bounds__(256) void conv1_k(const float* __restrict__ x,
                                               const float* __restrict__ W1,
                                               short* __restrict__ out) {
    __shared__ float wlds[1024];          // W1 [64 co][16 k] fp32
    int t = threadIdx.x;
    ((float4*)wlds)[t] = ((const float4*)W1)[t];
    __syncthreads();

    int pixel = blockIdx.x * 256 + t;     // 512*24*40 = 491520 pixels
    int n  = pixel / 960;
    int p  = pixel % 960;
    int oh = p / 40, ow = p % 40;
    int ih0 = oh * 2 - 1, iw0 = ow * 2 - 1;

    float patch[16];
#pragma unroll
    for (int kh = 0; kh < 4; ++kh) {
        int ih = ih0 + kh;
#pragma unroll
        for (int kw = 0; kw < 4; ++kw) {
            int iw = iw0 + kw;
            bool ok = ((unsigned)ih < 48u) && ((unsigned)iw < 80u);
            patch[kh * 4 + kw] = ok ? x[((size_t)n * 48 + ih) * 80 + iw] : 0.f;
        }
    }
#pragma unroll
    for (int cog = 0; cog < 8; ++cog) {
        bf16x8 v;
#pragma unroll
        for (int j = 0; j < 8; ++j) {
            const float4* wv = (const float4*)(wlds + (cog * 8 + j) * 16);
            float4 w0 = wv[0], w1 = wv[1], w2 = wv[2], w3 = wv[3];
            float a = 0.f;
            a = fmaf(patch[0],  w0.x, a); a = fmaf(patch[1],  w0.y, a);
            a = fmaf(patch[2],  w0.z, a); a = fmaf(patch[3],  w0.w, a);
            a = fmaf(patch[4],  w1.x, a); a = fmaf(patch[5],  w1.y, a);
            a = fmaf(patch[6],  w1.z, a); a = fmaf(patch[7],  w1.w, a);
            a = fmaf(patch[8],  w2.x, a); a = fmaf(patch[9],  w2.y, a);
            a = fmaf(patch[10], w2.z, a); a = fmaf(patch[11], w2.w, a);
            a = fmaf(patch[12], w3.x, a); a = fmaf(patch[13], w3.y, a);
            a = fmaf(patch[14], w3.z, a); a = fmaf(patch[15], w3.w, a);
            v[j] = f2bf(a);
        }
        *(bf16x8*)(out + (size_t)pixel * 64 + cog * 8) = v;
    }
}

// ---- conv2-4: MFMA implicit GEMM, BK templated, DMA staging, XCD swizzle ----
// CPR = BK/8 16B-chunks per row; SWM = CPR-1 swizzle mask (bijective per
// CPR-row stripe). BK must divide CIN.
template<int BKT, int CIN, int COUT, int IH, int IW, int OH, int OW>
__global__ __launch_bounds__(256, 4) void convM_k(const short* __restrict__ in,
                                                  const short* __restrict__ wB,
                                                  short* __restrict__ out,
                                                  float* __restrict__ part,
                                                  const short* __restrict__ zbuf) {
    constexpr int K  = CIN * 16;
    constexpr int NT = K / BKT;
    constexpr int BM = 128, BN = 64;
    constexpr int CPR = BKT / 8;          // chunks per row (8 or 16)
    constexpr int SWM = CPR - 1;          // swizzle mask (7 or 15)
    constexpr int RPS = 256 / CPR;        // rows per staging set (32 or 16)
    constexpr int RPW = 64 / CPR;         // rows per wave per set (8 or 4)
    constexpr int ASETS = BM / RPS;       // 4 or 8
    constexpr int BSETS = BN / RPS;       // 2 or 4
    constexpr int nTN = COUT / BN;
    constexpr int M = 512 * OH * OW;
    constexpr int NWG = (M / BM) * nTN;   // divisible by 8 for all layers
    __shared__ short As[BM * BKT];
    __shared__ short Bs[BN * BKT];

    const int t = threadIdx.x;
    // XCD-chunked swizzle: hw block b runs on XCD b&7.
    const int b = (int)blockIdx.x;
    const int lid = (b & 7) * (NWG >> 3) + (b >> 3);
    const int bn = lid % nTN;
    const int bm = lid / nTN;
    const int m0 = bm * BM, n0 = bn * BN;

    const int w = t >> 6, l = t & 63;
    // staging coordinates
    const int c   = t % CPR;              // chunk id within a row
    const int rs  = t / CPR;              // row-in-set (= w*RPW + l/CPR)
    const int rowlane = w * RPW + (l / CPR);
    const int ccs = c ^ (rowlane & SWM);  // pre-swizzled source chunk
    // hoisted A addressing: base offset + 16-bit (kh,kw) validity mask
    long aoff[ASETS];
    unsigned amask[ASETS];
#pragma unroll
    for (int i = 0; i < ASETS; ++i) {
        int row = i * RPS + rs;
        int gr = m0 + row;
        int n = gr / (OH * OW), p = gr % (OH * OW);
        int ph = (p / OW) * 2 - 1, pw = (p % OW) * 2 - 1;
        aoff[i] = ((long)n * IH * IW + (long)ph * IW + pw) * CIN + ccs * 8;
        unsigned m = 0;
#pragma unroll
        for (int kp = 0; kp < 16; ++kp) {
            int ih = ph + (kp >> 2), iw = pw + (kp & 3);
            if ((unsigned)ih < (unsigned)IH && (unsigned)iw < (unsigned)IW)
                m |= 1u << kp;
        }
        amask[i] = m;
    }
    long boff[BSETS];
#pragma unroll
    for (int i = 0; i < BSETS; ++i)
        boff[i] = (long)(n0 + i * RPS + rs) * K + ccs * 8;

    const int wr = (w >> 1) * 64, wc = (w & 1) * 32;
    const int fr = l & 15, kq = l >> 4;

    f32x4 acc[4][2];
#pragma unroll
    for (int mi = 0; mi < 4; ++mi)
#pragma unroll
        for (int ni = 0; ni < 2; ++ni) acc[mi][ni] = 0;

    for (int kt = 0; kt < NT; ++kt) {
        const int kk0 = kt * BKT;
        const int kp = kk0 / CIN, ci0 = kk0 % CIN;
        const long koff = ((long)(kp >> 2) * IW + (kp & 3)) * CIN + ci0;  // uniform
        __syncthreads();                  // all waves done reading LDS (prev kt)
#pragma unroll
        for (int i = 0; i < ASETS; ++i) {
            const short* src = ((amask[i] >> kp) & 1u)
                ? in + aoff[i] + koff : zbuf;
            gload16_lds(src, As + (i * RPS + w * RPW) * BKT);
        }
#pragma unroll
        for (int i = 0; i < BSETS; ++i)
            gload16_lds(wB + boff[i] + kk0, Bs + (i * RPS + w * RPW) * BKT);
        __syncthreads();                  // compiler drains vmcnt(0) pre-barrier
#pragma unroll
        for (int kk = 0; kk < BKT / 32; ++kk) {
            const int kidx = kk * 4 + kq;
            bf16x8 af[4], bfr[2];
#pragma unroll
            for (int mi = 0; mi < 4; ++mi) {
                int row = wr + mi * 16 + fr;
                af[mi] = *(const bf16x8*)(As + row * BKT + ((kidx ^ (row & SWM)) * 8));
            }
#pragma unroll
            for (int ni = 0; ni < 2; ++ni) {
                int row = wc + ni * 16 + fr;
                bfr[ni] = *(const bf16x8*)(Bs + row * BKT + ((kidx ^ (row & SWM)) * 8));
            }
#pragma unroll
            for (int mi = 0; mi < 4; ++mi)
#pragma unroll
                for (int ni = 0; ni < 2; ++ni)
                    acc[mi][ni] = __builtin_amdgcn_mfma_f32_16x16x32_bf16(
                        af[mi], bfr[ni], acc[mi][ni], 0, 0, 0);
        }
    }

    // bf16 output (D: row = kq*4+r, col = fr) + fused BN stage-1
#pragma unroll
    for (int mi = 0; mi < 4; ++mi)
#pragma unroll
        for (int ni = 0; ni < 2; ++ni)
#pragma unroll
            for (int r = 0; r < 4; ++r) {
                int row = m0 + wr + mi * 16 + kq * 4 + r;
                int col = n0 + wc + ni * 16 + fr;
                out[(size_t)row * COUT + col] = f2bf(acc[mi][ni][r]);
            }
    __syncthreads();                      // done reading As before aliasing
    float* red = (float*)As;              // 8 slots * 64 ch * 2 = 4 KB
#pragma unroll
    for (int ni = 0; ni < 2; ++ni) {
        float s = 0.f, q = 0.f;
#pragma unroll
        for (int mi = 0; mi < 4; ++mi)
#pragma unroll
            for (int r = 0; r < 4; ++r) {
                float v = acc[mi][ni][r];
                s += v; q = fmaf(v, v, q);
            }
        int slot = (w >> 1) * 4 + kq;
        int ch = wc + ni * 16 + fr;
        red[(slot * 64 + ch) * 2 + 0] = s;
        red[(slot * 64 + ch) * 2 + 1] = q;
    }
    __syncthreads();
    if (t < 64) {
        float s = 0.f, q = 0.f;
#pragma unroll
        for (int slot = 0; slot < 8; ++slot) {
            s += red[(slot * 64 + t) * 2 + 0];
            q += red[(slot * 64 + t) * 2 + 1];
        }
        part[(size_t)lid * 128 + t]      = s;    // logical-id indexed
        part[(size_t)lid * 128 + 64 + t] = q;
    }
}

// ---- BN stats stage 1 for h1 (bf16 input) ----
template<int C>
__global__ __launch_bounds__(256) void reduceB_k(const short* __restrict__ h,
                                                 float* __restrict__ part,
                                                 int R, int rpb) {
    constexpr int CG = C / 4;
    constexpr int STEP = 256 / CG;
    int t = threadIdx.x;
    int c4 = t % CG, rsub = t / CG;
    int r_lo = blockIdx.x * rpb, r_hi = min(R, r_lo + rpb);
    float s[4] = {0, 0, 0, 0}, q[4] = {0, 0, 0, 0};
    for (int r = r_lo + rsub; r < r_hi; r += STEP) {
        short4v v = *(const short4v*)(h + (size_t)r * C + c4 * 4);
#pragma unroll
        for (int j = 0; j < 4; ++j) { float f = bf2f(v[j]); s[j] += f; q[j] += f * f; }
    }
    __shared__ float ls[4][256], lq[4][256];
#pragma unroll
    for (int j = 0; j < 4; ++j) { ls[j][t] = s[j]; lq[j][t] = q[j]; }
    __syncthreads();
    for (int d = 128; d >= CG; d >>= 1) {
        if (t < d) {
#pragma unroll
            for (int j = 0; j < 4; ++j) { ls[j][t] += ls[j][t + d]; lq[j][t] += lq[j][t + d]; }
        }
        __syncthreads();
    }
    if (t < CG) {
#pragma unroll
        for (int j = 0; j < 4; ++j) {
            part[(size_t)blockIdx.x * 2 * C + c4 * 4 + j]     = ls[j][t];
            part[(size_t)blockIdx.x * 2 * C + C + c4 * 4 + j] = lq[j][t];
        }
    }
}

// ---- parallel stage-2 fold, reduceB layout (stride 2C per block) ----
template<int C, int P>
__global__ __launch_bounds__(1024) void statsP_k(const float* __restrict__ part,
                                                 const float* __restrict__ gamma,
                                                 const float* __restrict__ beta,
                                                 float* __restrict__ st,
                                                 int nblocks, float invR) {
    int t = threadIdx.x;
    int c = t % C, j = t / C;
    float s = 0.f, q = 0.f;
    for (int b = j; b < nblocks; b += P) {
        s += part[(size_t)b * 2 * C + c];
        q += part[(size_t)b * 2 * C + C + c];
    }
    __shared__ float ls[1024], lq[1024];
    ls[t] = s; lq[t] = q; __syncthreads();
    for (int d = C * P / 2; d >= C; d >>= 1) {
        if (t < d) { ls[t] += ls[t + d]; lq[t] += lq[t + d]; }
        __syncthreads();
    }
    if (t < C) {
        float mean = ls[t] * invR;
        float var  = lq[t] * invR - mean * mean;
        float sc = gamma[t] * rsqrtf(var + EPS);
        st[t]     = sc;
        st[C + t] = beta[t] - mean * sc;
    }
}

// ---- parallel stage-2 fold, convM fused-epilogue layout (2*64 per lid) ----
template<int C, int BNp, int P>
__global__ __launch_bounds__(1024) void stats2P_k(const float* __restrict__ part,
                                                  const float* __restrict__ gamma,
                                                  const float* __restrict__ beta,
                                                  float* __restrict__ st,
                                                  int nTM, float invR) {
    constexpr int NTN = C / BNp;
    int t = threadIdx.x;
    int c = t % C, j = t / C;
    int bn = c / BNp, cc = c % BNp;
    float s = 0.f, q = 0.f;
    for (int bm = j; bm < nTM; bm += P) {
        size_t idx = (size_t)(bm * NTN + bn) * (2 * BNp);
        s += part[idx + cc];
        q += part[idx + BNp + cc];
    }
    __shared__ float ls[1024], lq[1024];
    ls[t] = s; lq[t] = q; __syncthreads();
    for (int d = C * P / 2; d >= C; d >>= 1) {
        if (t < d) { ls[t] += ls[t + d]; lq[t] += lq[t + d]; }
        __syncthreads();
    }
    if (t < C) {
        float mean = ls[t] * invR;
        float var  = lq[t] * invR - mean * mean;
        float sc = gamma[t] * rsqrtf(var + EPS);
        st[t]     = sc;
        st[C + t] = beta[t] - mean * sc;
    }
}

// ---- in-place bf16 normalize + LeakyReLU ----
template<int C>
__global__ __launch_bounds__(256) void scaleB_k(short* __restrict__ h,
                                                const float* __restrict__ st,
                                                size_t n8) {
    __shared__ float sst[1024];
    int t = threadIdx.x;
    for (int j = t; j < 2 * C; j += 256) sst[j] = st[j];
    __syncthreads();
    size_t i = (size_t)blockIdx.x * 256 + t;
    size_t stride = (size_t)gridDim.x * 256;
    bf16x8* h8 = (bf16x8*)h;
    for (; i < n8; i += stride) {
        bf16x8 v = h8[i];
        int c0 = (int)((i * 8) & (size_t)(C - 1));
#pragma unroll
        for (int j = 0; j < 8; ++j) {
            float f = bf2f(v[j]);
            f = fmaf(f, sst[c0 + j], sst[C + c0 + j]);
            f = fmaxf(f, SLOPE * f);
            v[j] = f2bf(f);
        }
        h8[i] = v;
    }
}

// ---- expert head with fused st4 normalize+lrelu ----
__global__ __launch_bounds__(256) void head_k(const short* __restrict__ h4,
                                              const float* __restrict__ W5,
                                              const int* __restrict__ y,
                                              const float* __restrict__ st,
                                              float* __restrict__ out) {
    __shared__ float sst[1024];
    int t = threadIdx.x;
#pragma unroll
    for (int j = 0; j < 4; ++j) sst[t + j * 256] = st[t + j * 256];
    __syncthreads();
    int b = blockIdx.x;
    int e = y[b];
    const float* wp = W5 + (size_t)e * 7680;   // [512][3][5]: c*15 + hw
    const short* hb = h4 + (size_t)b * 7680;   // NHWC: hw*512 + c
    float s = 0.f;
    for (int f = t; f < 7680; f += 256) {
        int c  = f & 511;
        int hw = f >> 9;
        float hv = bf2f(hb[f]);
        hv = fmaf(hv, sst[c], sst[512 + c]);
        hv = fmaxf(hv, SLOPE * hv);
        s = fmaf(hv, wp[c * 15 + hw], s);
    }
    __shared__ float ls[256];
    ls[t] = s; __syncthreads();
    for (int d = 128; d > 0; d >>= 1) {
        if (t < d) ls[t] += ls[t + d];
        __syncthreads();
    }
    if (t == 0) out[b] = ls[0];
}

extern "C" void kernel_launch(void* const* d_in, const int* in_sizes, int n_in,
                              void* d_out, int out_size, void* d_ws, size_t ws_size,
                              hipStream_t stream) {
    const float* x  = (const float*)d_in[0];
    const float* W1 = (const float*)d_in[1];
    const float* g1 = (const float*)d_in[2];
    const float* b1 = (const float*)d_in[3];
    const float* W2 = (const float*)d_in[4];
    const float* g2 = (const float*)d_in[5];
    const float* b2 = (const float*)d_in[6];
    const float* W3 = (const float*)d_in[7];
    const float* g3 = (const float*)d_in[8];
    const float* b3 = (const float*)d_in[9];
    const float* W4 = (const float*)d_in[10];
    const float* g4 = (const float*)d_in[11];
    const float* b4 = (const float*)d_in[12];
    const float* W5 = (const float*)d_in[13];
    const int*   y  = (const int*)d_in[14];
    float* out = (float*)d_out;

    const size_t H1 = (size_t)512 * 24 * 40 * 64;
    const size_t H2 = (size_t)512 * 12 * 20 * 128;
    const size_t H3 = (size_t)512 * 6  * 10 * 256;
    const size_t H4 = (size_t)512 * 3  * 5  * 512;

    float* ws = (float*)d_ws;
    short* h1b = (short*)ws;
    short* h2b = (short*)(ws + H1 / 2);
    short* h3b = (short*)(ws + H1 / 2 + H2 / 2);
    short* h4b = (short*)(ws + H1 / 2 + H2 / 2 + H3 / 2);
    float* fbase = ws + H1 / 2 + H2 / 2 + H3 / 2 + H4 / 2;
    short* wB2 = (short*)fbase;                       // 131072 sh
    short* wB3 = (short*)(fbase + 65536);             // 524288 sh
    short* wB4 = (short*)(fbase + 65536 + 262144);    // 2097152 sh
    float* part = fbase + 65536 + 262144 + 1048576;   // 524288 f
    float* st1 = part + 524288;
    float* st2 = st1 + 128;
    float* st3 = st2 + 256;
    float* st4 = st3 + 512;
    float* zbuf = st4 + 1024;                         // 16 f = 64 B zero page

    const int NB = 512;

    // zero page for OOB staging reads (graph-capture-safe memset)
    hipMemsetAsync(zbuf, 0, 64, stream);

    // merged weight prep: (131072 + 524288 + 2097152) / 256 = 10752 blocks
    twkAll_k<<<10752, 256, 0, stream>>>(W2, W3, W4, wB2, wB3, wB4);

    // ---- L1 ----
    conv1_k<<<1920, 256, 0, stream>>>(x, W1, h1b);
    {
        int R = 512 * 24 * 40, rpb = (R + NB - 1) / NB;
        reduceB_k<64><<<NB, 256, 0, stream>>>(h1b, part, R, rpb);
        statsP_k<64, 16><<<1, 1024, 0, stream>>>(part, g1, b1, st1, NB, 1.f / R);
        scaleB_k<64><<<2048, 256, 0, stream>>>(h1b, st1, H1 / 8);
    }
    // ---- L2 ----  BK=64 (CIN bound): 960 m x 2 n = 1920 blocks
    convM_k<64, 64, 128, 24, 40, 12, 20><<<1920, 256, 0, stream>>>(
        h1b, wB2, h2b, part, (const short*)zbuf);
    {
        float invR = 1.f / (512 * 12 * 20);
        stats2P_k<128, 64, 8><<<1, 1024, 0, stream>>>(part, g2, b2, st2, 960, invR);
        scaleB_k<128><<<2048, 256, 0, stream>>>(h2b, st2, H2 / 8);
    }
    // ---- L3 ----  BK=128: 240 m x 4 n = 960 blocks, NT=16
    convM_k<128, 128, 256, 12, 20, 6, 10><<<960, 256, 0, stream>>>(
        h2b, wB3, h3b, part, (const short*)zbuf);
    {
        float invR = 1.f / (512 * 6 * 10);
        stats2P_k<256, 64, 4><<<1, 1024, 0, stream>>>(part, g3, b3, st3, 240, invR);
        scaleB_k<256><<<2048, 256, 0, stream>>>(h3b, st3, H3 / 8);
    }
    // ---- L4 ----  BK=128: 60 m x 8 n = 480 blocks, NT=32
    convM_k<128, 256, 512, 6, 10, 3, 5><<<480, 256, 0, stream>>>(
        h3b, wB4, h4b, part, (const short*)zbuf);
    {
        float invR = 1.f / (512 * 3 * 5);
        stats2P_k<512, 64, 2><<<1, 1024, 0, stream>>>(part, g4, b4, st4, 60, invR);
    }
    // ---- head (st4 fused) ----
    head_k<<<512, 256, 0, stream>>>(h4b, W5, y, st4, out);
}